// Round 10
// baseline (1444.429 us; speedup 1.0000x reference)
//
#include <hip/hip_runtime.h>

#define B_   128
#define S_   256
#define EMB_ 256
#define H_   1024
#define NH3  3072

#define G_      8      // batch groups
#define NW      32     // workgroups per group
#define MG      16     // batch rows per group
#define HS      32     // H output columns per workgroup
#define THREADS 768    // 12 waves

#define KP     1408    // padded K (f16): 352 u64 units x {3 data + tag}
#define KPB    2816    // bytes per padded LDS row
#define UPR    352     // u64 units per row
#define UW     11      // u64 units owned per WG per row
#define HPST   (128 * UPR)       // u64 per Hp buffer

typedef _Float16 f16;
typedef _Float16 h8 __attribute__((ext_vector_type(8)));
typedef float    f4 __attribute__((ext_vector_type(4)));
typedef unsigned long long u64;
typedef unsigned short u16;

#define AL64(pp) __hip_atomic_load((pp), __ATOMIC_RELAXED, __HIP_MEMORY_SCOPE_AGENT)

__device__ __forceinline__ u16 bit16(float v) {
  return __builtin_bit_cast(u16, (f16)v);
}
__device__ __forceinline__ unsigned pk2(float a, float b) {
  return (unsigned)bit16(a) | ((unsigned)bit16(b) << 16);
}

// ---------- transpose + fp16 convert: out[n*K + k] = (f16) in[k*N + n]
__global__ void transpose_cvt(const float* __restrict__ in, f16* __restrict__ out,
                              int K, int N) {
  __shared__ float tile[32][33];
  int n0 = blockIdx.x * 32, k0 = blockIdx.y * 32;
  int tx = threadIdx.x & 31, ty = threadIdx.x >> 5;
#pragma unroll
  for (int i = 0; i < 4; ++i)
    tile[ty + 8 * i][tx] = in[(k0 + ty + 8 * i) * N + n0 + tx];
  __syncthreads();
#pragma unroll
  for (int i = 0; i < 4; ++i)
    out[(n0 + ty + 8 * i) * K + k0 + tx] = (f16)tile[tx][ty + 8 * i];
}

// ---------- persistent GRU: tagged u64 exchange (race-free by construction)
__launch_bounds__(THREADS, 3)
__global__ void gru_kernel(const int* __restrict__ x, const float* __restrict__ emb,
                           const f16* __restrict__ Ut, const f16* __restrict__ Wt,
                           const float* __restrict__ hidden, const float* __restrict__ bvec,
                           float* __restrict__ out, u64* __restrict__ Hp) {
  __shared__ f16   h_lds[MG * KP];        // 45 KB padded slab, XOR-swizzled rows
  __shared__ f16   xe_lds[2][MG * EMB_];  // 16 KB
  __shared__ float recS[4][MG][100];      // K-split partials: z|r|xh
  __shared__ float recU[4][MG][36];       // K-split partials: rh

  const int tid = threadIdx.x;
  const int bid = blockIdx.x;
  const int g   = bid & 7;
  const int w   = bid >> 3;         // 0..31
  const int gb0 = g * MG;
  const int hc0 = w * HS;

  const int lane = tid & 63;
  const int wv   = tid >> 6;        // 0..11
  const int ksp  = wv & 3;          // K quarter
  const int cp   = wv >> 2;         // gate 0=z 1=r 2=hh
  const int ln   = lane & 15;
  const int klo  = lane >> 4;
  const int bl   = tid >> 5;        // gate row (tid<512)
  const int jl   = tid & 31;

  // ---- U fragments: padded-K layout built from Ut with zeros at tag/pad slots
  h8 uf0[UW], uf1[UW], wf0[2], wf1[2];
  {
    const f16* uc0 = Ut + (size_t)(cp * H_ + hc0 + ln) * H_;
    const f16* uc1 = uc0 + (size_t)16 * H_;
#pragma unroll
    for (int kt = 0; kt < UW; ++kt) {
      int pbase = ksp * 352 + kt * 32 + klo * 8;
      h8 r0, r1;
#pragma unroll
      for (int i = 0; i < 8; ++i) {
        int p = pbase + i, u = p >> 2, s = p & 3;
        int ww = u / 11, j = u - ww * 11, l = 3 * j + s;
        f16 v0 = (f16)0, v1 = (f16)0;
        if (s < 3 && l < 32) { v0 = uc0[32 * ww + l]; v1 = uc1[32 * ww + l]; }
        r0[i] = v0; r1[i] = v1;
      }
      uf0[kt] = r0; uf1[kt] = r1;
    }
    // FIX (round-9 bug): W fragment must include the K-quarter offset ksp*64
    const f16* w0 = Wt + (size_t)(cp * H_ + hc0 + ln) * EMB_ + ksp * 64 + klo * 8;
    const f16* w1 = w0 + 16 * EMB_;
#pragma unroll
    for (int kt = 0; kt < 2; ++kt) { wf0[kt] = *(const h8*)(w0 + kt * 32);
                                     wf1[kt] = *(const h8*)(w1 + kt * 32); }
  }
#pragma unroll
  for (int kt = 0; kt < UW; ++kt) { asm volatile("" : "+v"(uf0[kt])); asm volatile("" : "+v"(uf1[kt])); }
  asm volatile("" : "+v"(wf0[0]), "+v"(wf0[1]), "+v"(wf1[0]), "+v"(wf1[1]));

  // ---- per-thread gate state
  float hprev = 0.f, bz = 0.f, brr = 0.f, bxh = 0.f, brh = 0.f;
  size_t obase = 0, soff = 0;
  if (tid < 512) {
    int col = hc0 + jl;
    bz  = bvec[col] + bvec[NH3 + col];
    brr = bvec[H_ + col] + bvec[NH3 + H_ + col];
    bxh = bvec[2 * H_ + col];
    brh = bvec[NH3 + 2 * H_ + col];
    hprev = hidden[(size_t)(gb0 + bl) * H_ + col];
    obase = ((size_t)(gb0 + bl) * S_) * H_ + col;
    soff  = (size_t)(gb0 + bl) * H_ + col;
  }

  // ---- prologue: h(0) from hidden into padded LDS (tag slots = 0)
  for (int idx = tid; idx < MG * UPR; idx += THREADS) {
    int r = idx / UPR, u = idx - r * UPR;
    int ww = u / 11, j = u - ww * 11, l = 3 * j;
    const float* hp_ = hidden + (size_t)(gb0 + r) * H_ + 32 * ww + l;
    u16 d0 = bit16(hp_[0]);
    u16 d1 = bit16(hp_[1]);                       // l+1 <= 31 always
    u16 d2 = (l + 2 < 32) ? bit16(hp_[2]) : (u16)0;
    u64 wd = (u64)d0 | ((u64)d1 << 16) | ((u64)d2 << 32);
    *(u64*)((char*)h_lds + r * KPB + ((u * 8) ^ ((r & 7) << 4))) = wd;
  }
  // ---- prologue: xe(0) from emb
  if (tid < 256) {
    int rr = tid >> 4, cc = tid & 15;
    int xrow = x[(gb0 + rr) * S_];
    const float4* ep = (const float4*)(emb + (size_t)xrow * EMB_) + cc * 4;
    float4 e0 = ep[0], e1 = ep[1], e2 = ep[2], e3 = ep[3];
    uint4 v0 = { pk2(e0.x, e0.y), pk2(e0.z, e0.w), pk2(e1.x, e1.y), pk2(e1.z, e1.w) };
    uint4 v1 = { pk2(e2.x, e2.y), pk2(e2.z, e2.w), pk2(e3.x, e3.y), pk2(e3.z, e3.w) };
    int c0 = cc * 2;
    *(uint4*)((char*)xe_lds[0] + rr * 512 + ((c0 * 16) ^ ((rr & 7) << 4))) = v0;
    *(uint4*)((char*)xe_lds[0] + rr * 512 + (((c0 + 1) * 16) ^ ((rr & 7) << 4))) = v1;
  }
  __syncthreads();

  for (int t = 0; t < S_; ++t) {
    // ---- pull h(t) tagged slab (t>0): batched load + batched retry
    if (t > 0) {
      const u64* src = Hp + (size_t)(t % 3) * HPST + (size_t)gb0 * UPR;
      const u16 want = (u16)t;
      u64 v[8];
#pragma unroll
      for (int k = 0; k < 7; ++k) v[k] = AL64(src + tid + k * 768);
      if (tid < 256) v[7] = AL64(src + tid + 5376);
      for (;;) {
        bool bad = false;
#pragma unroll
        for (int k = 0; k < 8; ++k)
          if ((k < 7 || tid < 256) && (u16)(v[k] >> 48) != want) bad = true;
        if (!bad) break;
        __builtin_amdgcn_s_sleep(1);
#pragma unroll
        for (int k = 0; k < 8; ++k)
          if ((k < 7 || tid < 256) && (u16)(v[k] >> 48) != want)
            v[k] = AL64(src + tid + k * 768);
      }
#pragma unroll
      for (int k = 0; k < 8; ++k) {
        if (k < 7 || tid < 256) {
          int idx = tid + k * 768;
          int r = idx / UPR, u = idx - r * UPR;
          *(u64*)((char*)h_lds + r * KPB + ((u * 8) ^ ((r & 7) << 4))) = v[k];
        }
      }
      __syncthreads();
    }

    // ---- MFMA: U (2 N-tiles x 11 kt, padded-K) + W (2 N-tiles x 2 kt)
    f4 a0 = {0.f,0.f,0.f,0.f}, a1 = {0.f,0.f,0.f,0.f};
    f4 a2 = {0.f,0.f,0.f,0.f}, a3 = {0.f,0.f,0.f,0.f};
    const char* hb = (const char*)h_lds + ln * KPB;
    const char* xb = (const char*)xe_lds[t & 1] + ln * 512;
    const int rm = (ln & 7) << 4;
#pragma unroll
    for (int kt = 0; kt < UW; ++kt) {
      h8 a = *(const h8*)(hb + ((ksp * 704 + kt * 64 + klo * 16) ^ rm));
      a0 = __builtin_amdgcn_mfma_f32_16x16x32_f16(a, uf0[kt], a0, 0, 0, 0);
      a1 = __builtin_amdgcn_mfma_f32_16x16x32_f16(a, uf1[kt], a1, 0, 0, 0);
    }
#pragma unroll
    for (int kt = 0; kt < 2; ++kt) {
      h8 a = *(const h8*)(xb + ((ksp * 128 + kt * 64 + klo * 16) ^ rm));
      a2 = __builtin_amdgcn_mfma_f32_16x16x32_f16(a, wf0[kt], a2, 0, 0, 0);
      a3 = __builtin_amdgcn_mfma_f32_16x16x32_f16(a, wf1[kt], a3, 0, 0, 0);
    }
#pragma unroll
    for (int j = 0; j < 4; ++j) {
      int r = klo * 4 + j;
      if (cp < 2) {
        recS[ksp][r][cp * 32 + ln]      = a0[j] + a2[j];
        recS[ksp][r][cp * 32 + 16 + ln] = a1[j] + a3[j];
      } else {
        recS[ksp][r][64 + ln] = a2[j];
        recS[ksp][r][80 + ln] = a3[j];
        recU[ksp][r][ln]      = a0[j];
        recU[ksp][r][16 + ln] = a1[j];
      }
    }
    __syncthreads();

    // ---- gates + tagged publish (fire & forget, no drain/flag/poll)
    float outv = 0.f;
    if (tid < 512) {
      float az = recS[0][bl][jl] + recS[1][bl][jl] + recS[2][bl][jl] + recS[3][bl][jl] + bz;
      float ar = recS[0][bl][32+jl] + recS[1][bl][32+jl] + recS[2][bl][32+jl] + recS[3][bl][32+jl] + brr;
      float xh = recS[0][bl][64+jl] + recS[1][bl][64+jl] + recS[2][bl][64+jl] + recS[3][bl][64+jl] + bxh;
      float rhu = recU[0][bl][jl] + recU[1][bl][jl] + recU[2][bl][jl] + recU[3][bl][jl] + brh;
      float z  = 1.f / (1.f + __expf(-az));
      float r  = 1.f / (1.f + __expf(-ar));
      float hh = 1.f - 2.f / (1.f + __expf(2.f * (xh + r * rhu)));
      float hn = z * hprev + (1.f - z) * hh;
      hprev = hn; outv = hn;
      if (t < S_ - 1) {
        float s1 = __shfl(hn, lane + 1);
        float s2 = __shfl(hn, lane + 2);
        if (jl % 3 == 0 && jl < 31) {
          int j = jl / 3;
          u64 wd = (u64)bit16(hn) | ((u64)bit16(s1) << 16)
                 | ((u64)(jl == 30 ? (u16)0 : bit16(s2)) << 32)
                 | ((u64)(u16)(t + 1) << 48);
          __hip_atomic_store(Hp + (size_t)((t + 1) % 3) * HPST + (size_t)(gb0 + bl) * UPR
                               + UW * w + j,
                             wd, __ATOMIC_RELAXED, __HIP_MEMORY_SCOPE_AGENT);
        }
      }
    }
    if (t == S_ - 1) {
      if (tid < 512) {
        out[obase + (size_t)t * H_] = outv;
        out[(size_t)B_ * S_ * H_ + soff] = outv;
      }
      break;
    }

    // ---- visibility window: out stores + next xe gather from emb
    if (tid < 512) {
      out[obase + (size_t)t * H_] = outv;
    } else {
      int thr = tid - 512;
      int rr = thr >> 4, cc = thr & 15;
      int xrow = x[(gb0 + rr) * S_ + t + 1];
      const float4* ep = (const float4*)(emb + (size_t)xrow * EMB_) + cc * 4;
      float4 e0 = ep[0], e1 = ep[1], e2 = ep[2], e3 = ep[3];
      uint4 v0 = { pk2(e0.x, e0.y), pk2(e0.z, e0.w), pk2(e1.x, e1.y), pk2(e1.z, e1.w) };
      uint4 v1 = { pk2(e2.x, e2.y), pk2(e2.z, e2.w), pk2(e3.x, e3.y), pk2(e3.z, e3.w) };
      char* dst = (char*)xe_lds[(t + 1) & 1];
      int c0 = cc * 2;
      *(uint4*)(dst + rr * 512 + ((c0 * 16) ^ ((rr & 7) << 4))) = v0;
      *(uint4*)(dst + rr * 512 + (((c0 + 1) * 16) ^ ((rr & 7) << 4))) = v1;
    }
    // no sync needed here: h_lds was last read before the post-recS barrier,
    // and nothing reads xe_lds[(t+1)&1] until after the next pull barrier.
  }
}

extern "C" void kernel_launch(void* const* d_in, const int* in_sizes, int n_in,
                              void* d_out, int out_size, void* d_ws, size_t ws_size,
                              hipStream_t stream) {
  const int*   x      = (const int*)  d_in[0];
  const float* hidden = (const float*)d_in[1];
  const float* emb    = (const float*)d_in[2];
  const float* W      = (const float*)d_in[3];
  const float* U      = (const float*)d_in[4];
  const float* bvec   = (const float*)d_in[5];
  float* out = (float*)d_out;

  char* ws = (char*)d_ws;
  f16* Ut  = (f16*)(ws);                 // 6,291,456 B
  f16* Wt  = (f16*)(ws + 6291456);       // 1,572,864 B
  u64* Hp  = (u64*)(ws + 7864320);       // 3 x 360,448 B tagged buffers

  hipMemsetAsync(Hp, 0, 3 * HPST * 8, stream);
  hipLaunchKernelGGL(transpose_cvt, dim3(NH3 / 32, H_ / 32), dim3(256), 0, stream,
                     U, Ut, H_, NH3);
  hipLaunchKernelGGL(transpose_cvt, dim3(NH3 / 32, EMB_ / 32), dim3(256), 0, stream,
                     W, Wt, EMB_, NH3);

  void* args[] = { (void*)&x, (void*)&emb, (void*)&Ut, (void*)&Wt,
                   (void*)&hidden, (void*)&bvec, (void*)&out, (void*)&Hp };
  hipLaunchCooperativeKernel(reinterpret_cast<void*>(gru_kernel),
                             dim3(G_ * NW), dim3(THREADS), args, 0, stream);
}

// Round 11
// 1058.003 us; speedup vs baseline: 1.3652x; 1.3652x over previous
//
#include <hip/hip_runtime.h>

#define B_   128
#define S_   256
#define EMB_ 256
#define H_   1024
#define NH3  3072

#define MG      16    // rows per subgroup
#define HS      16    // H columns per workgroup
#define THREADS 768   // 12 waves

typedef _Float16 f16;
typedef _Float16 h8 __attribute__((ext_vector_type(8)));
typedef float    f4 __attribute__((ext_vector_type(4)));
typedef unsigned long long u64;

#define AL64(pp) __hip_atomic_load((pp), __ATOMIC_RELAXED, __HIP_MEMORY_SCOPE_AGENT)

// ---------- gather + fp16 convert
__global__ void gather_kernel(const int* __restrict__ x, const float* __restrict__ emb,
                              f16* __restrict__ xe16) {
  int m = blockIdx.x, k = threadIdx.x;
  int b = m & 127, s = m >> 7;
  int row = x[b * S_ + s];
  xe16[m * EMB_ + k] = (f16)emb[row * EMB_ + k];
}

// ---------- transpose + fp16 convert: out[n*K + k] = (f16) in[k*N + n]
__global__ void transpose_cvt(const float* __restrict__ in, f16* __restrict__ out,
                              int K, int N) {
  __shared__ float tile[32][33];
  int n0 = blockIdx.x * 32, k0 = blockIdx.y * 32;
  int tx = threadIdx.x & 31, ty = threadIdx.x >> 5;
#pragma unroll
  for (int i = 0; i < 4; ++i)
    tile[ty + 8 * i][tx] = in[(k0 + ty + 8 * i) * N + n0 + tx];
  __syncthreads();
#pragma unroll
  for (int i = 0; i < 4; ++i)
    out[(n0 + ty + 8 * i) * K + k0 + tx] = (f16)tile[tx][ty + 8 * i];
}

// ---------- persistent GRU: pair-interleaved, strict serial poll->pull protocol
__launch_bounds__(THREADS, 3)
__global__ void gru_kernel(const f16* __restrict__ xe16, const f16* __restrict__ Ut,
                           const f16* __restrict__ Wt, const float* __restrict__ hidden,
                           const float* __restrict__ bvec, float* __restrict__ out,
                           f16* __restrict__ h16, int* __restrict__ flags) {
  __shared__ f16   h_lds[2][MG * H_];     // A,B slabs: 2 x 32 KB, rows 2048B swizzled
  __shared__ f16   xe_lds[2][MG * EMB_];  // A,B xe: 2 x 8 KB, rows 512B swizzled
  __shared__ float recS[4][MG][68];       // K-split partials z|r|xh|rh (reused A/B)

  const int tid = threadIdx.x;
  const int bid = blockIdx.x;
  const int p   = bid & 3;          // pair
  const int w   = bid >> 2;         // 0..63 producer id within pair
  const int hc0 = w * HS;
  const int rowA = p * 32, rowB = p * 32 + 16;

  const int lane = tid & 63;
  const int wv   = tid >> 6;        // 0..11
  const int ksp  = wv & 3;          // K quarter
  const int cp   = wv >> 2;         // gate 0=z 1=r 2=hh
  const int ln   = lane & 15;
  const int klo  = lane >> 4;
  const int bl   = tid >> 4;        // gate row (tid<256)
  const int jl   = tid & 15;        // gate col

  int* flA = flags + p * 128;
  int* flB = flags + p * 128 + 64;

  // ---- weights register-resident: per wave one gate x one 16-col N-tile x K-quarter
  h8 uf[8]; h8 wf[2];
  {
    const f16* u0 = Ut + (size_t)(cp * H_ + hc0 + ln) * H_ + ksp * 256 + klo * 8;
#pragma unroll
    for (int kt = 0; kt < 8; ++kt) uf[kt] = *(const h8*)(u0 + kt * 32);
    const f16* w0 = Wt + (size_t)(cp * H_ + hc0 + ln) * EMB_ + ksp * 64 + klo * 8;
    wf[0] = *(const h8*)(w0);
    wf[1] = *(const h8*)(w0 + 32);
  }
#pragma unroll
  for (int kt = 0; kt < 8; ++kt) asm volatile("" : "+v"(uf[kt]));
  asm volatile("" : "+v"(wf[0]), "+v"(wf[1]));

  // ---- per-thread gate state (tid<256)
  float hprevA = 0.f, hprevB = 0.f, bz = 0.f, brr = 0.f, bxh = 0.f, brh = 0.f;
  size_t obaseA = 0, obaseB = 0, soffA = 0, soffB = 0;
  if (tid < 256) {
    int col = hc0 + jl;
    bz  = bvec[col] + bvec[NH3 + col];
    brr = bvec[H_ + col] + bvec[NH3 + H_ + col];
    bxh = bvec[2 * H_ + col];
    brh = bvec[NH3 + 2 * H_ + col];
    hprevA = hidden[(size_t)(rowA + bl) * H_ + col];
    hprevB = hidden[(size_t)(rowB + bl) * H_ + col];
    obaseA = ((size_t)(rowA + bl) * S_) * H_ + col;
    obaseB = ((size_t)(rowB + bl) * S_) * H_ + col;
    soffA  = (size_t)(rowA + bl) * H_ + col;
    soffB  = (size_t)(rowB + bl) * H_ + col;
  }

  // ---- prologue: stage A(0), B(0) from hidden; xe(0) for both
  for (int idx = tid; idx < 2 * MG * H_ / 4; idx += THREADS) {  // 8192 float4
    int grp = idx >> 12, i = idx & 4095;
    int r = i >> 8, c4 = i & 255;
    float4 hv = ((const float4*)(hidden + (size_t)(p * 32 + grp * 16 + r) * H_))[c4];
    unsigned lo = ((unsigned)__builtin_bit_cast(unsigned short, (f16)hv.y) << 16)
                |  (unsigned)__builtin_bit_cast(unsigned short, (f16)hv.x);
    unsigned hi = ((unsigned)__builtin_bit_cast(unsigned short, (f16)hv.w) << 16)
                |  (unsigned)__builtin_bit_cast(unsigned short, (f16)hv.z);
    uint2 pk = {lo, hi};
    *(uint2*)((char*)h_lds[grp] + r * 2048 + ((c4 * 8) ^ ((r & 7) << 4))) = pk;
  }
  for (int idx = tid; idx < 2 * MG * EMB_ / 8; idx += THREADS) { // 1024 uint4
    int grp = idx >> 9, i = idx & 511;
    int r = i >> 5, c = i & 31;
    uint4 v = ((const uint4*)(xe16 + (size_t)(p * 32 + grp * 16) * EMB_))[i];
    *(uint4*)((char*)xe_lds[grp] + r * 512 + ((c * 16) ^ ((r & 7) << 4))) = v;
  }
  __syncthreads();

#define MFMA_PHASE(GRP)                                                          \
  {                                                                              \
    f4 aU = {0.f,0.f,0.f,0.f}, aW = {0.f,0.f,0.f,0.f};                           \
    const char* hb = (const char*)h_lds[GRP] + ln * 2048;                        \
    const char* xb = (const char*)xe_lds[GRP] + ln * 512;                        \
    const int rm = (ln & 7) << 4;                                                \
    _Pragma("unroll")                                                            \
    for (int kt = 0; kt < 8; ++kt) {                                             \
      h8 a = *(const h8*)(hb + ((ksp * 512 + kt * 64 + klo * 16) ^ rm));         \
      aU = __builtin_amdgcn_mfma_f32_16x16x32_f16(a, uf[kt], aU, 0, 0, 0);       \
    }                                                                            \
    _Pragma("unroll")                                                            \
    for (int kt = 0; kt < 2; ++kt) {                                             \
      h8 a = *(const h8*)(xb + ((ksp * 128 + kt * 64 + klo * 16) ^ rm));         \
      aW = __builtin_amdgcn_mfma_f32_16x16x32_f16(a, wf[kt], aW, 0, 0, 0);       \
    }                                                                            \
    _Pragma("unroll")                                                            \
    for (int j = 0; j < 4; ++j) {                                                \
      int r = klo * 4 + j;                                                       \
      if (cp == 0)      recS[ksp][r][ln]      = aU[j] + aW[j];                   \
      else if (cp == 1) recS[ksp][r][16 + ln] = aU[j] + aW[j];                   \
      else { recS[ksp][r][32 + ln] = aW[j]; recS[ksp][r][48 + ln] = aU[j]; }     \
    }                                                                            \
  }

#define GATES(hprev, outv)                                                       \
  {                                                                              \
    float az = recS[0][bl][jl] + recS[1][bl][jl] + recS[2][bl][jl]               \
             + recS[3][bl][jl] + bz;                                             \
    float ar = recS[0][bl][16+jl] + recS[1][bl][16+jl] + recS[2][bl][16+jl]      \
             + recS[3][bl][16+jl] + brr;                                         \
    float xh = recS[0][bl][32+jl] + recS[1][bl][32+jl] + recS[2][bl][32+jl]      \
             + recS[3][bl][32+jl] + bxh;                                         \
    float rhu = recS[0][bl][48+jl] + recS[1][bl][48+jl] + recS[2][bl][48+jl]     \
              + recS[3][bl][48+jl] + brh;                                        \
    float z  = 1.f / (1.f + __expf(-az));                                        \
    float r  = 1.f / (1.f + __expf(-ar));                                        \
    float hh = 1.f - 2.f / (1.f + __expf(2.f * (xh + r * rhu)));                 \
    float hn = z * hprev + (1.f - z) * hh;                                       \
    hprev = hn; outv = hn;                                                       \
  }

  // serial proven pull: poll (all waves, lane->flag) THEN load slab -> LDS
#define PULL(GRP, rowbase, buf, FL, NEED)                                        \
  {                                                                              \
    for (;;) {                                                                   \
      int f = AL64((FL) + lane);                                                 \
      if (__all(f >= (NEED))) break;                                             \
      __builtin_amdgcn_s_sleep(1);                                               \
    }                                                                            \
    const u64* src = (const u64*)(h16 + (size_t)(buf) * (B_ * H_)                \
                                  + (size_t)(rowbase) * H_);                     \
    u64 v0 = AL64(src + tid);        u64 v1 = AL64(src + tid + 768);             \
    u64 v2 = AL64(src + tid + 1536); u64 v3 = AL64(src + tid + 2304);            \
    u64 v4 = AL64(src + tid + 3072); u64 v5 = 0;                                 \
    if (tid < 256) v5 = AL64(src + 3840 + tid);                                  \
    { int i_ = tid;        int r_ = i_ >> 8, c_ = i_ & 255;                      \
      *(u64*)((char*)h_lds[GRP] + r_ * 2048 + ((c_ * 8) ^ ((r_ & 7) << 4))) = v0; } \
    { int i_ = tid + 768;  int r_ = i_ >> 8, c_ = i_ & 255;                      \
      *(u64*)((char*)h_lds[GRP] + r_ * 2048 + ((c_ * 8) ^ ((r_ & 7) << 4))) = v1; } \
    { int i_ = tid + 1536; int r_ = i_ >> 8, c_ = i_ & 255;                      \
      *(u64*)((char*)h_lds[GRP] + r_ * 2048 + ((c_ * 8) ^ ((r_ & 7) << 4))) = v2; } \
    { int i_ = tid + 2304; int r_ = i_ >> 8, c_ = i_ & 255;                      \
      *(u64*)((char*)h_lds[GRP] + r_ * 2048 + ((c_ * 8) ^ ((r_ & 7) << 4))) = v3; } \
    { int i_ = tid + 3072; int r_ = i_ >> 8, c_ = i_ & 255;                      \
      *(u64*)((char*)h_lds[GRP] + r_ * 2048 + ((c_ * 8) ^ ((r_ & 7) << 4))) = v4; } \
    if (tid < 256) { int i_ = 3840 + tid; int r_ = i_ >> 8, c_ = i_ & 255;       \
      *(u64*)((char*)h_lds[GRP] + r_ * 2048 + ((c_ * 8) ^ ((r_ & 7) << 4))) = v5; } \
  }

#define XE_STAGE(GRP, rowbase)                                                   \
  {                                                                              \
    const uint4* xs = (const uint4*)(xe16 + ((size_t)(t + 1) * B_ + (rowbase)) * EMB_); \
    char* dst = (char*)xe_lds[GRP];                                              \
    int i0 = (tid - 512) * 2;                                                    \
    uint4 x0 = xs[i0], x1 = xs[i0 + 1];                                          \
    { int r_ = i0 >> 5, c_ = i0 & 31;                                            \
      *(uint4*)(dst + r_ * 512 + ((c_ * 16) ^ ((r_ & 7) << 4))) = x0; }          \
    { int i1 = i0 + 1; int r_ = i1 >> 5, c_ = i1 & 31;                           \
      *(uint4*)(dst + r_ * 512 + ((c_ * 16) ^ ((r_ & 7) << 4))) = x1; }          \
  }

  for (int t = 0; t < S_; ++t) {
    const int nb = (t + 1) & 1;     // buffer holding h(t+1)
    //================ phase 1: MFMA A(t) ================
    MFMA_PHASE(0)
    __syncthreads();
    //================ phase 2: gates A, publish A(t+1), xe A(t+1) ================
    if (tid < 256) {
      float outvA;
      GATES(hprevA, outvA)
      if (t < S_ - 1) {
        unsigned short hb16 = __builtin_bit_cast(unsigned short, (f16)outvA);
        __hip_atomic_store((unsigned short*)h16 + (size_t)nb * (B_ * H_) + soffA,
                           hb16, __ATOMIC_RELAXED, __HIP_MEMORY_SCOPE_AGENT);
      }
      out[obaseA + (size_t)t * H_] = outvA;
      if (t == S_ - 1) out[(size_t)B_ * S_ * H_ + soffA] = outvA;
    } else if (tid >= 512 && t < S_ - 1) {
      XE_STAGE(0, rowA)
    }
    //================ phase 3: pull B(t) [strict poll->load]; flag A(t+1) ========
    if (t > 0) PULL(1, rowB, t & 1, flB, t)
    asm volatile("s_waitcnt vmcnt(0)" ::: "memory");
    __syncthreads();
    if (t < S_ - 1 && tid == 0)
      __hip_atomic_store(&flA[w], t + 1, __ATOMIC_RELAXED, __HIP_MEMORY_SCOPE_AGENT);
    //================ phase 5: MFMA B(t) ================
    MFMA_PHASE(1)
    __syncthreads();
    //================ phase 6: gates B, publish B(t+1), xe B(t+1) ================
    if (tid < 256) {
      float outvB;
      GATES(hprevB, outvB)
      if (t < S_ - 1) {
        unsigned short hb16 = __builtin_bit_cast(unsigned short, (f16)outvB);
        __hip_atomic_store((unsigned short*)h16 + (size_t)nb * (B_ * H_) + soffB,
                           hb16, __ATOMIC_RELAXED, __HIP_MEMORY_SCOPE_AGENT);
      }
      out[obaseB + (size_t)t * H_] = outvB;
      if (t == S_ - 1) out[(size_t)B_ * S_ * H_ + soffB] = outvB;
    } else if (tid >= 512 && t < S_ - 1) {
      XE_STAGE(1, rowB)
    }
    //================ phase 7-8: pull A(t+1); flag B(t+1) ================
    if (t < S_ - 1) {
      PULL(0, rowA, nb, flA, t + 1)
      asm volatile("s_waitcnt vmcnt(0)" ::: "memory");
      __syncthreads();
      if (tid == 0)
        __hip_atomic_store(&flB[w], t + 1, __ATOMIC_RELAXED, __HIP_MEMORY_SCOPE_AGENT);
    }
  }
}

extern "C" void kernel_launch(void* const* d_in, const int* in_sizes, int n_in,
                              void* d_out, int out_size, void* d_ws, size_t ws_size,
                              hipStream_t stream) {
  const int*   x      = (const int*)  d_in[0];
  const float* hidden = (const float*)d_in[1];
  const float* emb    = (const float*)d_in[2];
  const float* W      = (const float*)d_in[3];
  const float* U      = (const float*)d_in[4];
  const float* bvec   = (const float*)d_in[5];
  float* out = (float*)d_out;

  char* ws = (char*)d_ws;
  f16* Ut    = (f16*)(ws);                   //  6,291,456 B
  f16* Wt    = (f16*)(ws + 6291456);         //  1,572,864 B
  f16* xe16  = (f16*)(ws + 7864320);         // 16,777,216 B
  f16* h16   = (f16*)(ws + 24641536);        //    524,288 B (double buffer)
  int* flags = (int*)(ws + 25165824);        //  4*128*4 = 2048 B

  hipMemsetAsync(flags, 0, 2048, stream);
  hipLaunchKernelGGL(transpose_cvt, dim3(NH3 / 32, H_ / 32), dim3(256), 0, stream,
                     U, Ut, H_, NH3);
  hipLaunchKernelGGL(transpose_cvt, dim3(NH3 / 32, EMB_ / 32), dim3(256), 0, stream,
                     W, Wt, EMB_, NH3);
  hipLaunchKernelGGL(gather_kernel, dim3(B_ * S_), dim3(EMB_), 0, stream, x, emb, xe16);

  void* args[] = { (void*)&xe16, (void*)&Ut, (void*)&Wt, (void*)&hidden,
                   (void*)&bvec, (void*)&out, (void*)&h16, (void*)&flags };
  hipLaunchCooperativeKernel(reinterpret_cast<void*>(gru_kernel),
                             dim3(256), dim3(THREADS), args, 0, stream);
}